// Round 3
// baseline (149.431 us; speedup 1.0000x reference)
//
#include <hip/hip_runtime.h>
#include <hip/hip_bf16.h>

#define BATCH 4
#define SEQ   2048
#define DM    512
#define NH    8
#define HD    64
#define PART  (BATCH*NH*SEQ*HD)   /* 4,194,304 = M*DM */
#define QSCALE 0.18033688f        /* (1/sqrt(64)) * log2(e) : folded into Q */

typedef unsigned short u16;
typedef unsigned int   u32;
typedef __bf16 bf16x8 __attribute__((ext_vector_type(8)));
typedef float  f32x4  __attribute__((ext_vector_type(4)));
typedef float  f32x16 __attribute__((ext_vector_type(16)));
typedef unsigned int u32x2 __attribute__((ext_vector_type(2)));

__device__ __forceinline__ u16 f2bf(float f) {
    union { float f; u32 u; } v; v.f = f;
    u32 r = v.u + 0x7fffu + ((v.u >> 16) & 1u);   // RNE
    return (u16)(r >> 16);
}

// async global->LDS, 16B per lane; LDS dest = uniform base + lane*16
__device__ __forceinline__ void glds16(const u16* g, u16* lds) {
    __builtin_amdgcn_global_load_lds(
        (const __attribute__((address_space(1))) void*)g,
        (__attribute__((address_space(3))) void*)lds, 16, 0, 0);
}

// v_permlane32_swap_b32: a.hi-lanes <-> b.lo-lanes
__device__ __forceinline__ void pl32swap(u32 &a, u32 &b) {
    u32x2 r = __builtin_amdgcn_permlane32_swap(a, b, false, false);
    a = r[0]; b = r[1];
}

// ---------------------------------------------------------------------------
// prep: z=0 -> f32->bf16 convert of x (512 blocks, grid-stride)
//       z=1 -> transpose w_qkv (192 blocks)   z=2 -> transpose w_out (64)
// ---------------------------------------------------------------------------
__global__ __launch_bounds__(256) void prep_k(
    const float* __restrict__ x, u16* __restrict__ xb,
    const float* __restrict__ w_qkv, u16* __restrict__ t_qkv,
    const float* __restrict__ w_out, u16* __restrict__ t_out)
{
    __shared__ u16 Ts[64][72];
    const int z = blockIdx.z, bx = blockIdx.x, t = threadIdx.x;

    if (z == 0) {
        const int n8 = PART / 8;
        for (int i = bx * 256 + t; i < n8; i += 512 * 256) {
            float4 a = *(const float4*)(x + (size_t)i * 8);
            float4 b = *(const float4*)(x + (size_t)i * 8 + 4);
            union { uint4 v; u16 s[8]; } o;
            o.s[0] = f2bf(a.x); o.s[1] = f2bf(a.y);
            o.s[2] = f2bf(a.z); o.s[3] = f2bf(a.w);
            o.s[4] = f2bf(b.x); o.s[5] = f2bf(b.y);
            o.s[6] = f2bf(b.z); o.s[7] = f2bf(b.w);
            *(uint4*)(xb + (size_t)i * 8) = o.v;
        }
        return;
    }
    const int N = (z == 1) ? 3 * DM : DM;
    const int ntiles = N / 64;
    if (bx >= ntiles * 8) return;
    const float* W = (z == 1) ? w_qkv : w_out;
    u16* Wt = (z == 1) ? t_qkv : t_out;
    const int n0 = (bx % ntiles) * 64, k0 = (bx / ntiles) * 64;

    #pragma unroll
    for (int l = 0; l < 4; ++l) {
        int idx = l * 1024 + t * 4;
        int r = idx >> 6, c = idx & 63;
        float4 v = *(const float4*)(W + (size_t)(k0 + r) * N + n0 + c);
        Ts[c + 0][r] = f2bf(v.x);
        Ts[c + 1][r] = f2bf(v.y);
        Ts[c + 2][r] = f2bf(v.z);
        Ts[c + 3][r] = f2bf(v.w);
    }
    __syncthreads();
    #pragma unroll
    for (int l = 0; l < 2; ++l) {
        int idx = l * 256 + t;
        int row = idx >> 3, ch = idx & 7;
        *(uint4*)(Wt + (size_t)(n0 + row) * DM + k0 + ch * 8) =
            *(const uint4*)(&Ts[row][ch * 8]);
    }
}

// ---------------------------------------------------------------------------
// GEMM: C(M,N) = A(M,K)bf16 @ Bt(N,K)^T bf16 + bias(N)f32.
// Double-buffered LDS, one barrier per K-step.
// MODE 0: BM=128; scatter into ws: Q (prescaled) | K (B,H,S,HD); V^T (B,H,HD,S).
// MODE 1: BM=64 (grid 128x4 = 512 blocks, 2/CU); row-major f32 store.
// ---------------------------------------------------------------------------
template<int MODE>
__global__ __launch_bounds__(256) void gemm_k(
    const u16* __restrict__ A, const u16* __restrict__ Bt,
    const float* __restrict__ bias, void* __restrict__ outv,
    int M, int N, int K)
{
    constexpr int BM = (MODE == 1) ? 64 : 128;
    constexpr int NI = (MODE == 1) ? 2 : 4;

    __shared__ __align__(16) u16 As[2][BM * 32];
    __shared__ __align__(16) u16 Bs[2][128 * 32];

    const int tid  = threadIdx.x;
    const int bm0  = blockIdx.x * BM;
    const int bn0  = blockIdx.y * 128;
    const int wave = tid >> 6, lane = tid & 63;
    const int l16  = lane & 15, quad = lane >> 4;
    const int wr   = (MODE == 1) ? 0 : (wave & 1) * 64;
    const int wc   = (MODE == 1) ? wave * 32 : (wave >> 1) * 64;

    const int srow = (lane >> 2);            // 0..15
    const int scol = (lane & 3) * 8;         // 0,8,16,24
    const int arow = (MODE == 1) ? (wave * 16) : (wave * 32);
    const u16* Ag = A + (size_t)(bm0 + arow + srow) * K + scol;
    const u16* Bg = Bt + (size_t)(bn0 + wave * 32 + srow) * K + scol;
    const int wofsA = arow * 32;
    const int wofsB = (wave * 32) * 32;

    f32x4 acc[4][NI];
    #pragma unroll
    for (int i = 0; i < 4; ++i)
        #pragma unroll
        for (int j = 0; j < NI; ++j)
            acc[i][j] = (f32x4){0.f, 0.f, 0.f, 0.f};

    glds16(Ag, &As[0][wofsA]);
    if (MODE == 0) glds16(Ag + (size_t)16 * K, &As[0][wofsA + 16 * 32]);
    glds16(Bg,                  &Bs[0][wofsB]);
    glds16(Bg + (size_t)16 * K, &Bs[0][wofsB + 16 * 32]);
    __syncthreads();

    const int NIT = K >> 5;
    for (int it = 0; it < NIT; ++it) {
        const int cur = it & 1;
        if (it + 1 < NIT) {
            const int nx = cur ^ 1;
            const int k0 = (it + 1) << 5;
            glds16(Ag + k0, &As[nx][wofsA]);
            if (MODE == 0) glds16(Ag + k0 + (size_t)16 * K, &As[nx][wofsA + 16 * 32]);
            glds16(Bg + k0,                  &Bs[nx][wofsB]);
            glds16(Bg + k0 + (size_t)16 * K, &Bs[nx][wofsB + 16 * 32]);
        }

        bf16x8 af[4], bfr[NI];
        #pragma unroll
        for (int mi = 0; mi < 4; ++mi)
            af[mi] = *(const bf16x8*)(&As[cur][(wr + mi * 16 + l16) * 32 + quad * 8]);
        #pragma unroll
        for (int ni = 0; ni < NI; ++ni)
            bfr[ni] = *(const bf16x8*)(&Bs[cur][(wc + ni * 16 + l16) * 32 + quad * 8]);
        #pragma unroll
        for (int mi = 0; mi < 4; ++mi)
            #pragma unroll
            for (int ni = 0; ni < NI; ++ni)
                acc[mi][ni] = __builtin_amdgcn_mfma_f32_16x16x32_bf16(
                    af[mi], bfr[ni], acc[mi][ni], 0, 0, 0);
        __syncthreads();
    }

    #pragma unroll
    for (int mi = 0; mi < 4; ++mi) {
        #pragma unroll
        for (int ni = 0; ni < NI; ++ni) {
            int col = bn0 + wc + ni * 16 + l16;
            float bv = bias[col];
            int row0 = bm0 + wr + mi * 16 + quad * 4;
            float v[4];
            #pragma unroll
            for (int reg = 0; reg < 4; ++reg) v[reg] = acc[mi][ni][reg] + bv;

            if (MODE == 1) {
                #pragma unroll
                for (int reg = 0; reg < 4; ++reg)
                    ((float*)outv)[(size_t)(row0 + reg) * N + col] = v[reg];
            } else {
                u16* ws = (u16*)outv;
                int part = col >> 9, wi = col & 511;
                int h = wi >> 6, e = wi & 63;
                int b = row0 >> 11, s0 = row0 & 2047;
                if (part == 2) {
                    union { u16 q[4]; uint2 u; } pk;
                    #pragma unroll
                    for (int reg = 0; reg < 4; ++reg) pk.q[reg] = f2bf(v[reg]);
                    *(uint2*)(ws + (size_t)2 * PART +
                              ((size_t)(b * NH + h) * HD + e) * SEQ + s0) = pk.u;
                } else {
                    float scl = (part == 0) ? QSCALE : 1.0f;
                    #pragma unroll
                    for (int reg = 0; reg < 4; ++reg)
                        ws[(size_t)part * PART +
                           ((size_t)(b * NH + h) * SEQ + s0 + reg) * HD + e] =
                            f2bf(v[reg] * scl);
                }
            }
        }
    }
}

// ---------------------------------------------------------------------------
// Causal flash attention, swapped-QK 32x32 MFMA, in-register P (T12),
// NOW with depth-2 prefetch: 3 LDS buffers + counted vmcnt(4) + raw s_barrier
// (T3/T4) so global_load_lds stays in flight ACROSS the per-tile barrier.
// Per iter: vmcnt(4) [oldest tile landed] -> s_barrier -> issue DMA(kt+2)
// into the buffer freed last iter -> compute buf[kt%3]. DMA has 2 compute
// phases to cover HBM/L2 latency. Q/O VMEM ops are drained by the
// phase-boundary __syncthreads, keeping the vmcnt arithmetic exact.
// ---------------------------------------------------------------------------
__global__ __launch_bounds__(256, 2) void attn_k(
    const u16* __restrict__ Q, const u16* __restrict__ K,
    const u16* __restrict__ Vt, u16* __restrict__ O)
{
    __shared__ __align__(16) u16 KsB[3][64 * 64];   // [kv][d], chunk-swizzled
    __shared__ __align__(16) u16 VtB[3][64 * 64];   // [d][kv], chunk-swizzled
    __shared__ float Lred[4][32];

    const int bh   = blockIdx.x;
    const int pair = blockIdx.y;               // 0..15
    const int tid = threadIdx.x, wave = tid >> 6, lane = tid & 63;
    const int l31 = lane & 31, hi = lane >> 5, x7 = lane & 7;
    const int qh = wave >> 1, kh = wave & 1;
    const size_t baseK = (size_t)bh * SEQ * HD;
    const size_t baseV = (size_t)bh * HD * SEQ;
    const int b = bh >> 3, h = bh & 7;

    // glds lane source addressing (XOR chunk swizzle at the source)
    const int sub = lane >> 3;                 // 0..7
    const int lcx = (lane & 7) ^ sub;          // logical 16B chunk for this lane
    const u16* kg = K  + baseK + (size_t)((wave * 16 + sub) * 64)   + lcx * 8;
    const u16* vg = Vt + baseV + (size_t)((wave * 16 + sub) * 2048) + lcx * 8;
    u16* ks0 = &KsB[0][wave * 1024];           // wave-uniform DMA bases
    u16* vt0 = &VtB[0][wave * 1024];

    // fragment LDS element offsets (swizzle: phys chunk = logical ^ (row&7); row&7 == lane&7)
    int koff[4], voff[2][2];
    #pragma unroll
    for (int k = 0; k < 4; ++k)
        koff[k] = (kh * 32 + l31) * 64 + ((((k << 1) + hi)) ^ x7) * 8;
    #pragma unroll
    for (int dt = 0; dt < 2; ++dt)
        #pragma unroll
        for (int k0 = 0; k0 < 2; ++k0)
            voff[dt][k0] = (dt * 32 + l31) * 64 + ((kh * 4 + k0 * 2 + hi) ^ x7) * 8;

    #pragma unroll
    for (int phase = 0; phase < 2; ++phase) {
        const int qt = phase ? pair : (31 - pair);   // 33 iters total/block

        // ---- Q fragments direct from global (rows q = qh*32+l31, d = hi*8 + 16k) ----
        const u16* qg = Q + baseK + (size_t)(qt * 64 + qh * 32 + l31) * 64 + hi * 8;
        bf16x8 qf[4];
        #pragma unroll
        for (int k = 0; k < 4; ++k)
            qf[k] = *(const bf16x8*)(qg + k * 16);

        __syncthreads();   // epilogue LDS reads done + full vmcnt drain

        // ---- prologue: prefetch kt=0 -> buf0, kt=1 -> buf1 ----
        glds16(kg,            ks0);
        glds16(kg + 8 * 64,   ks0 + 512);
        glds16(vg,            vt0);
        glds16(vg + 8 * 2048, vt0 + 512);
        if (qt >= 1) {
            glds16(kg + 4096,          ks0 + 4096);
            glds16(kg + 4096 + 8 * 64, ks0 + 4096 + 512);
            glds16(vg + 64,            vt0 + 4096);
            glds16(vg + 64 + 8 * 2048, vt0 + 4096 + 512);
        }

        float la0 = 0.f, la1 = 0.f;
        f32x16 o0, o1;
        #pragma unroll
        for (int i = 0; i < 16; ++i) { o0[i] = 0.f; o1[i] = 0.f; }

        int bcur = 0;
        for (int kt = 0; kt <= qt; ++kt) {
            // counted wait: oldest in-flight tile (kt) landed; newest stays out
            if (kt < qt) asm volatile("s_waitcnt vmcnt(4)" ::: "memory");
            else         asm volatile("s_waitcnt vmcnt(0)" ::: "memory");
            __builtin_amdgcn_s_barrier();
            asm volatile("" ::: "memory");

            if (kt + 2 <= qt) {                 // issue into buffer freed last iter
                int bi = bcur + 2; if (bi >= 3) bi -= 3;
                u16* kd = ks0 + bi * 4096;
                u16* vd = vt0 + bi * 4096;
                const size_t ko = (size_t)(kt + 2) * 4096;
                const size_t vo = (size_t)(kt + 2) * 64;
                glds16(kg + ko,            kd);
                glds16(kg + ko + 8 * 64,   kd + 512);
                glds16(vg + vo,            vd);
                glds16(vg + vo + 8 * 2048, vd + 512);
            }

            const bool diag = (kt == qt);
            if (!(diag && kh > qh)) {        // (qh=0,kh=1) diag tile fully masked
                const u16* Kb = &KsB[bcur][0];
                const u16* Vb = &VtB[bcur][0];
                bf16x8 kf[4], vf[2][2];
                #pragma unroll
                for (int k = 0; k < 4; ++k)
                    kf[k] = *(const bf16x8*)(&Kb[koff[k]]);
                #pragma unroll
                for (int dt = 0; dt < 2; ++dt)
                    #pragma unroll
                    for (int k0 = 0; k0 < 2; ++k0)
                        vf[dt][k0] = *(const bf16x8*)(&Vb[voff[dt][k0]]);

                // S^T = K @ Q^T : col = q (lane&31), row = kv
                f32x16 st;
                #pragma unroll
                for (int i = 0; i < 16; ++i) st[i] = 0.f;
                __builtin_amdgcn_s_setprio(1);
                #pragma unroll
                for (int k = 0; k < 4; ++k)
                    st = __builtin_amdgcn_mfma_f32_32x32x16_bf16(
                        kf[k], qf[k], st, 0, 0, 0);
                __builtin_amdgcn_s_setprio(0);

                // p[r] at kv_local = (r&3) + 8*(r>>2) + 4*hi, q = l31
                float p[16];
                #pragma unroll
                for (int r = 0; r < 16; ++r)
                    p[r] = __builtin_amdgcn_exp2f(st[r]);
                if (diag && kh == qh) {      // triangular mask on the diagonal
                    #pragma unroll
                    for (int r = 0; r < 16; ++r) {
                        int kvl = (r & 3) + 8 * (r >> 2) + 4 * hi;
                        if (kvl > l31) p[r] = 0.f;
                    }
                }
                #pragma unroll
                for (int r = 0; r < 8; ++r) { la0 += p[r]; la1 += p[r + 8]; }

                // pack to bf16 pairs; permlane32_swap builds PV A-fragments
                u32 c[8];
                #pragma unroll
                for (int m = 0; m < 8; ++m) {
                    __hip_bfloat162 t =
                        __float22bfloat162_rn(float2{p[2 * m], p[2 * m + 1]});
                    c[m] = *(u32*)&t;
                }
                pl32swap(c[0], c[2]); pl32swap(c[1], c[3]);
                pl32swap(c[4], c[6]); pl32swap(c[5], c[7]);
                union { u32 w[4]; bf16x8 v; } pa0, pa1;
                pa0.w[0] = c[0]; pa0.w[1] = c[1]; pa0.w[2] = c[2]; pa0.w[3] = c[3];
                pa1.w[0] = c[4]; pa1.w[1] = c[5]; pa1.w[2] = c[6]; pa1.w[3] = c[7];

                // O[q][d] += P @ V   (A = P, B = V from Vt tile)
                __builtin_amdgcn_s_setprio(1);
                o0 = __builtin_amdgcn_mfma_f32_32x32x16_bf16(pa0.v, vf[0][0], o0, 0, 0, 0);
                o0 = __builtin_amdgcn_mfma_f32_32x32x16_bf16(pa1.v, vf[0][1], o0, 0, 0, 0);
                o1 = __builtin_amdgcn_mfma_f32_32x32x16_bf16(pa0.v, vf[1][0], o1, 0, 0, 0);
                o1 = __builtin_amdgcn_mfma_f32_32x32x16_bf16(pa1.v, vf[1][1], o1, 0, 0, 0);
                __builtin_amdgcn_s_setprio(0);
            }
            bcur = (bcur == 2) ? 0 : bcur + 1;
        }
        __syncthreads();   // all compute reads done before Ob scratch reuse

        // ---- merge kv-halves (pure sums): l via Lred, o via K/V LDS reuse ----
        float l2 = (la0 + la1);
        l2 += __shfl_xor(l2, 32);            // combine hi halves (same q)
        if (lane < 32) Lred[wave][lane] = l2;
        float* Ob = (qh == 0) ? (float*)&KsB[0][0] : (float*)&VtB[0][0];
        if (kh == 1) {
            #pragma unroll
            for (int r = 0; r < 16; ++r) {
                Ob[r * 64 + lane]        = o0[r];
                Ob[(16 + r) * 64 + lane] = o1[r];
            }
        }
        __syncthreads();
        if (kh == 0) {
            #pragma unroll
            for (int r = 0; r < 16; ++r) {
                int ql = (r & 3) + 8 * (r >> 2) + 4 * hi;       // q row 0..31
                float lt = Lred[2 * qh][ql] + Lred[2 * qh + 1][ql];
                int srow = qt * 64 + qh * 32 + ql;
                size_t idx = (((size_t)(b * SEQ + srow)) * NH + h) * HD + l31;
                float v0 = (o0[r] + Ob[r * 64 + lane]) / lt;
                float v1 = (o1[r] + Ob[(16 + r) * 64 + lane]) / lt;
                O[idx]      = f2bf(v0);
                O[idx + 32] = f2bf(v1);
            }
        }
    }
}

extern "C" void kernel_launch(void* const* d_in, const int* in_sizes, int n_in,
                              void* d_out, int out_size, void* d_ws, size_t ws_size,
                              hipStream_t stream) {
    const float* x     = (const float*)d_in[0];
    const float* w_qkv = (const float*)d_in[1];
    const float* b_qkv = (const float*)d_in[2];
    const float* w_out = (const float*)d_in[3];
    const float* b_out = (const float*)d_in[4];

    u16* qkv    = (u16*)d_ws;                       // Q | K | V^T, each PART
    u16* attn   = qkv + (size_t)3 * PART;           // PART bf16 (B,S,H,HD)
    u16* xb     = attn + (size_t)PART;              // PART bf16 (x converted)
    u16* wt_qkv = xb + (size_t)PART;                // 1536*512 bf16
    u16* wt_out = wt_qkv + (size_t)(3 * DM) * DM;   // 512*512 bf16

    const int M = BATCH * SEQ;                      // 8192

    prep_k<<<dim3(512, 1, 3), 256, 0, stream>>>(x, xb, w_qkv, wt_qkv,
                                                w_out, wt_out);

    dim3 g1(M / 128, (3 * DM) / 128);               // 64 x 12
    gemm_k<0><<<g1, 256, 0, stream>>>(xb, wt_qkv, b_qkv, qkv, M, 3 * DM, DM);

    dim3 g2(BATCH * NH, 16);                        // bh x pair (uniform work)
    attn_k<<<g2, 256, 0, stream>>>(qkv, qkv + PART, qkv + 2 * (size_t)PART, attn);

    dim3 g3(M / 64, DM / 128);                      // 128 x 4 = 512 blocks
    gemm_k<1><<<g3, 256, 0, stream>>>(attn, wt_out, b_out, (float*)d_out, M, DM, DM);
}

// Round 4
// 145.834 us; speedup vs baseline: 1.0247x; 1.0247x over previous
//
#include <hip/hip_runtime.h>
#include <hip/hip_bf16.h>

#define BATCH 4
#define SEQ   2048
#define DM    512
#define NH    8
#define HD    64
#define PART  (BATCH*NH*SEQ*HD)   /* 4,194,304 = M*DM */
#define QSCALE 0.18033688f        /* (1/sqrt(64)) * log2(e) : folded into Q */

typedef unsigned short u16;
typedef unsigned int   u32;
typedef __bf16 bf16x8 __attribute__((ext_vector_type(8)));
typedef float  f32x4  __attribute__((ext_vector_type(4)));
typedef float  f32x16 __attribute__((ext_vector_type(16)));
typedef unsigned int u32x2 __attribute__((ext_vector_type(2)));

__device__ __forceinline__ u16 f2bf(float f) {
    union { float f; u32 u; } v; v.f = f;
    u32 r = v.u + 0x7fffu + ((v.u >> 16) & 1u);   // RNE
    return (u16)(r >> 16);
}

// async global->LDS, 16B per lane; LDS dest = uniform base + lane*16
__device__ __forceinline__ void glds16(const u16* g, u16* lds) {
    __builtin_amdgcn_global_load_lds(
        (const __attribute__((address_space(1))) void*)g,
        (__attribute__((address_space(3))) void*)lds, 16, 0, 0);
}

// v_permlane32_swap_b32: a.hi-lanes <-> b.lo-lanes
__device__ __forceinline__ void pl32swap(u32 &a, u32 &b) {
    u32x2 r = __builtin_amdgcn_permlane32_swap(a, b, false, false);
    a = r[0]; b = r[1];
}

// ---------------------------------------------------------------------------
// prep: z=0 -> f32->bf16 convert of x (512 blocks, grid-stride)
//       z=1 -> transpose w_qkv (192 blocks)   z=2 -> transpose w_out (64)
// ---------------------------------------------------------------------------
__global__ __launch_bounds__(256) void prep_k(
    const float* __restrict__ x, u16* __restrict__ xb,
    const float* __restrict__ w_qkv, u16* __restrict__ t_qkv,
    const float* __restrict__ w_out, u16* __restrict__ t_out)
{
    __shared__ u16 Ts[64][72];
    const int z = blockIdx.z, bx = blockIdx.x, t = threadIdx.x;

    if (z == 0) {
        const int n8 = PART / 8;
        for (int i = bx * 256 + t; i < n8; i += 512 * 256) {
            float4 a = *(const float4*)(x + (size_t)i * 8);
            float4 b = *(const float4*)(x + (size_t)i * 8 + 4);
            union { uint4 v; u16 s[8]; } o;
            o.s[0] = f2bf(a.x); o.s[1] = f2bf(a.y);
            o.s[2] = f2bf(a.z); o.s[3] = f2bf(a.w);
            o.s[4] = f2bf(b.x); o.s[5] = f2bf(b.y);
            o.s[6] = f2bf(b.z); o.s[7] = f2bf(b.w);
            *(uint4*)(xb + (size_t)i * 8) = o.v;
        }
        return;
    }
    const int N = (z == 1) ? 3 * DM : DM;
    const int ntiles = N / 64;
    if (bx >= ntiles * 8) return;
    const float* W = (z == 1) ? w_qkv : w_out;
    u16* Wt = (z == 1) ? t_qkv : t_out;
    const int n0 = (bx % ntiles) * 64, k0 = (bx / ntiles) * 64;

    #pragma unroll
    for (int l = 0; l < 4; ++l) {
        int idx = l * 1024 + t * 4;
        int r = idx >> 6, c = idx & 63;
        float4 v = *(const float4*)(W + (size_t)(k0 + r) * N + n0 + c);
        Ts[c + 0][r] = f2bf(v.x);
        Ts[c + 1][r] = f2bf(v.y);
        Ts[c + 2][r] = f2bf(v.z);
        Ts[c + 3][r] = f2bf(v.w);
    }
    __syncthreads();
    #pragma unroll
    for (int l = 0; l < 2; ++l) {
        int idx = l * 256 + t;
        int row = idx >> 3, ch = idx & 7;
        *(uint4*)(Wt + (size_t)(n0 + row) * DM + k0 + ch * 8) =
            *(const uint4*)(&Ts[row][ch * 8]);
    }
}

// ---------------------------------------------------------------------------
// GEMM: C(M,N) = A(M,K)bf16 @ Bt(N,K)^T bf16 + bias(N)f32.
// Double-buffered LDS, one barrier per K-step.
// MODE 0: BM=128; scatter into ws: Q (prescaled) | K (B,H,S,HD); V^T (B,H,HD,S).
// MODE 1: BM=64 (grid 128x4 = 512 blocks, 2/CU); row-major f32 store.
// ---------------------------------------------------------------------------
template<int MODE>
__global__ __launch_bounds__(256) void gemm_k(
    const u16* __restrict__ A, const u16* __restrict__ Bt,
    const float* __restrict__ bias, void* __restrict__ outv,
    int M, int N, int K)
{
    constexpr int BM = (MODE == 1) ? 64 : 128;
    constexpr int NI = (MODE == 1) ? 2 : 4;

    __shared__ __align__(16) u16 As[2][BM * 32];
    __shared__ __align__(16) u16 Bs[2][128 * 32];

    const int tid  = threadIdx.x;
    const int bm0  = blockIdx.x * BM;
    const int bn0  = blockIdx.y * 128;
    const int wave = tid >> 6, lane = tid & 63;
    const int l16  = lane & 15, quad = lane >> 4;
    const int wr   = (MODE == 1) ? 0 : (wave & 1) * 64;
    const int wc   = (MODE == 1) ? wave * 32 : (wave >> 1) * 64;

    const int srow = (lane >> 2);            // 0..15
    const int scol = (lane & 3) * 8;         // 0,8,16,24
    const int arow = (MODE == 1) ? (wave * 16) : (wave * 32);
    const u16* Ag = A + (size_t)(bm0 + arow + srow) * K + scol;
    const u16* Bg = Bt + (size_t)(bn0 + wave * 32 + srow) * K + scol;
    const int wofsA = arow * 32;
    const int wofsB = (wave * 32) * 32;

    f32x4 acc[4][NI];
    #pragma unroll
    for (int i = 0; i < 4; ++i)
        #pragma unroll
        for (int j = 0; j < NI; ++j)
            acc[i][j] = (f32x4){0.f, 0.f, 0.f, 0.f};

    glds16(Ag, &As[0][wofsA]);
    if (MODE == 0) glds16(Ag + (size_t)16 * K, &As[0][wofsA + 16 * 32]);
    glds16(Bg,                  &Bs[0][wofsB]);
    glds16(Bg + (size_t)16 * K, &Bs[0][wofsB + 16 * 32]);
    __syncthreads();

    const int NIT = K >> 5;
    for (int it = 0; it < NIT; ++it) {
        const int cur = it & 1;
        if (it + 1 < NIT) {
            const int nx = cur ^ 1;
            const int k0 = (it + 1) << 5;
            glds16(Ag + k0, &As[nx][wofsA]);
            if (MODE == 0) glds16(Ag + k0 + (size_t)16 * K, &As[nx][wofsA + 16 * 32]);
            glds16(Bg + k0,                  &Bs[nx][wofsB]);
            glds16(Bg + k0 + (size_t)16 * K, &Bs[nx][wofsB + 16 * 32]);
        }

        bf16x8 af[4], bfr[NI];
        #pragma unroll
        for (int mi = 0; mi < 4; ++mi)
            af[mi] = *(const bf16x8*)(&As[cur][(wr + mi * 16 + l16) * 32 + quad * 8]);
        #pragma unroll
        for (int ni = 0; ni < NI; ++ni)
            bfr[ni] = *(const bf16x8*)(&Bs[cur][(wc + ni * 16 + l16) * 32 + quad * 8]);
        #pragma unroll
        for (int mi = 0; mi < 4; ++mi)
            #pragma unroll
            for (int ni = 0; ni < NI; ++ni)
                acc[mi][ni] = __builtin_amdgcn_mfma_f32_16x16x32_bf16(
                    af[mi], bfr[ni], acc[mi][ni], 0, 0, 0);
        __syncthreads();
    }

    #pragma unroll
    for (int mi = 0; mi < 4; ++mi) {
        #pragma unroll
        for (int ni = 0; ni < NI; ++ni) {
            int col = bn0 + wc + ni * 16 + l16;
            float bv = bias[col];
            int row0 = bm0 + wr + mi * 16 + quad * 4;
            float v[4];
            #pragma unroll
            for (int reg = 0; reg < 4; ++reg) v[reg] = acc[mi][ni][reg] + bv;

            if (MODE == 1) {
                #pragma unroll
                for (int reg = 0; reg < 4; ++reg)
                    ((float*)outv)[(size_t)(row0 + reg) * N + col] = v[reg];
            } else {
                u16* ws = (u16*)outv;
                int part = col >> 9, wi = col & 511;
                int h = wi >> 6, e = wi & 63;
                int b = row0 >> 11, s0 = row0 & 2047;
                if (part == 2) {
                    union { u16 q[4]; uint2 u; } pk;
                    #pragma unroll
                    for (int reg = 0; reg < 4; ++reg) pk.q[reg] = f2bf(v[reg]);
                    *(uint2*)(ws + (size_t)2 * PART +
                              ((size_t)(b * NH + h) * HD + e) * SEQ + s0) = pk.u;
                } else {
                    float scl = (part == 0) ? QSCALE : 1.0f;
                    #pragma unroll
                    for (int reg = 0; reg < 4; ++reg)
                        ws[(size_t)part * PART +
                           ((size_t)(b * NH + h) * SEQ + s0 + reg) * HD + e] =
                            f2bf(v[reg] * scl);
                }
            }
        }
    }
}

// ---------------------------------------------------------------------------
// Causal flash attention, swapped-QK 32x32 MFMA, in-register P (T12).
// OCCUPANCY round: grid (bh=32, y=32), ONE q-tile per block (qt = 31-y,
// big-first for LPT scheduling), 2 LDS buffers (33 KB) + launch_bounds
// (256,4) -> 4 blocks/CU = 16 waves/CU (2x round-3's TLP). The serial
// dep chain (ds_read -> 4 chained QK MFMA -> exp2 -> pack -> permlane ->
// 4 chained PV MFMA) is latency-hidden by co-resident blocks, not by
// in-wave scheduling (rounds 2/3 proved scheduling alone is neutral).
// Same-bh blocks are 32 apart in linear id -> same XCD (32 % 8 == 0):
// K/V stay L2-local (4 bh x 512 KB = 2 MB per XCD L2).
// ---------------------------------------------------------------------------
__global__ __launch_bounds__(256, 4) void attn_k(
    const u16* __restrict__ Q, const u16* __restrict__ K,
    const u16* __restrict__ Vt, u16* __restrict__ O)
{
    __shared__ __align__(16) u16 KsB[2][64 * 64];   // [kv][d], chunk-swizzled
    __shared__ __align__(16) u16 VtB[2][64 * 64];   // [d][kv], chunk-swizzled
    __shared__ float Lred[4][32];

    const int bh = blockIdx.x;
    const int qt = 31 - blockIdx.y;            // big q-tiles dispatched first
    const int tid = threadIdx.x, wave = tid >> 6, lane = tid & 63;
    const int l31 = lane & 31, hi = lane >> 5, x7 = lane & 7;
    const int qh = wave >> 1, kh = wave & 1;
    const size_t baseK = (size_t)bh * SEQ * HD;
    const size_t baseV = (size_t)bh * HD * SEQ;
    const int b = bh >> 3, h = bh & 7;

    // glds lane source addressing (XOR chunk swizzle at the source)
    const int sub = lane >> 3;                 // 0..7
    const int lcx = (lane & 7) ^ sub;          // logical 16B chunk for this lane
    const u16* kg = K  + baseK + (size_t)((wave * 16 + sub) * 64)   + lcx * 8;
    const u16* vg = Vt + baseV + (size_t)((wave * 16 + sub) * 2048) + lcx * 8;
    u16* ksd = &KsB[0][wave * 1024];
    u16* vtd = &VtB[0][wave * 1024];

    // fragment LDS element offsets (swizzle: phys chunk = logical ^ (row&7); row&7 == lane&7)
    int koff[4], voff[2][2];
    #pragma unroll
    for (int k = 0; k < 4; ++k)
        koff[k] = (kh * 32 + l31) * 64 + ((((k << 1) + hi)) ^ x7) * 8;
    #pragma unroll
    for (int dt = 0; dt < 2; ++dt)
        #pragma unroll
        for (int k0 = 0; k0 < 2; ++k0)
            voff[dt][k0] = (dt * 32 + l31) * 64 + ((kh * 4 + k0 * 2 + hi) ^ x7) * 8;

    // ---- Q fragments direct from global (rows q = qh*32+l31, d = hi*8 + 16k) ----
    const u16* qg = Q + baseK + (size_t)(qt * 64 + qh * 32 + l31) * 64 + hi * 8;
    bf16x8 qf[4];
    #pragma unroll
    for (int k = 0; k < 4; ++k)
        qf[k] = *(const bf16x8*)(qg + k * 16);

    // prefetch kt=0 into buffer 0
    glds16(kg,            ksd);
    glds16(kg + 8 * 64,   ksd + 512);
    glds16(vg,            vtd);
    glds16(vg + 8 * 2048, vtd + 512);
    __syncthreads();   // vmcnt(0) drain: buf0 landed

    float la0 = 0.f, la1 = 0.f;
    f32x16 o0, o1;
    #pragma unroll
    for (int i = 0; i < 16; ++i) { o0[i] = 0.f; o1[i] = 0.f; }

    for (int kt = 0; kt <= qt; ++kt) {
        const int cur = kt & 1;
        if (kt < qt) {
            const int nx = (cur ^ 1) * 4096;
            glds16(kg + (size_t)(kt + 1) * 4096,          ksd + nx);
            glds16(kg + (size_t)(kt + 1) * 4096 + 8 * 64, ksd + nx + 512);
            glds16(vg + (size_t)(kt + 1) * 64,            vtd + nx);
            glds16(vg + (size_t)(kt + 1) * 64 + 8 * 2048, vtd + nx + 512);
        }

        const bool diag = (kt == qt);
        if (!(diag && kh > qh)) {        // (qh=0,kh=1) diag tile fully masked
            bf16x8 kf[4], vf[2][2];
            #pragma unroll
            for (int k = 0; k < 4; ++k)
                kf[k] = *(const bf16x8*)(&KsB[cur][koff[k]]);
            #pragma unroll
            for (int dt = 0; dt < 2; ++dt)
                #pragma unroll
                for (int k0 = 0; k0 < 2; ++k0)
                    vf[dt][k0] = *(const bf16x8*)(&VtB[cur][voff[dt][k0]]);

            // S^T = K @ Q^T : col = q (lane&31), row = kv
            f32x16 st;
            #pragma unroll
            for (int i = 0; i < 16; ++i) st[i] = 0.f;
            __builtin_amdgcn_s_setprio(1);
            #pragma unroll
            for (int k = 0; k < 4; ++k)
                st = __builtin_amdgcn_mfma_f32_32x32x16_bf16(
                    kf[k], qf[k], st, 0, 0, 0);
            __builtin_amdgcn_s_setprio(0);

            // p[r] at kv_local = (r&3) + 8*(r>>2) + 4*hi, q = l31
            float p[16];
            #pragma unroll
            for (int r = 0; r < 16; ++r)
                p[r] = __builtin_amdgcn_exp2f(st[r]);
            if (diag && kh == qh) {      // triangular mask on the diagonal
                #pragma unroll
                for (int r = 0; r < 16; ++r) {
                    int kvl = (r & 3) + 8 * (r >> 2) + 4 * hi;
                    if (kvl > l31) p[r] = 0.f;
                }
            }
            #pragma unroll
            for (int r = 0; r < 8; ++r) { la0 += p[r]; la1 += p[r + 8]; }

            // pack to bf16 pairs; permlane32_swap builds PV A-fragments
            u32 c[8];
            #pragma unroll
            for (int m = 0; m < 8; ++m) {
                __hip_bfloat162 t =
                    __float22bfloat162_rn(float2{p[2 * m], p[2 * m + 1]});
                c[m] = *(u32*)&t;
            }
            pl32swap(c[0], c[2]); pl32swap(c[1], c[3]);
            pl32swap(c[4], c[6]); pl32swap(c[5], c[7]);
            union { u32 w[4]; bf16x8 v; } pa0, pa1;
            pa0.w[0] = c[0]; pa0.w[1] = c[1]; pa0.w[2] = c[2]; pa0.w[3] = c[3];
            pa1.w[0] = c[4]; pa1.w[1] = c[5]; pa1.w[2] = c[6]; pa1.w[3] = c[7];

            // O[q][d] += P @ V   (A = P, B = V from Vt tile)
            __builtin_amdgcn_s_setprio(1);
            o0 = __builtin_amdgcn_mfma_f32_32x32x16_bf16(pa0.v, vf[0][0], o0, 0, 0, 0);
            o0 = __builtin_amdgcn_mfma_f32_32x32x16_bf16(pa1.v, vf[0][1], o0, 0, 0, 0);
            o1 = __builtin_amdgcn_mfma_f32_32x32x16_bf16(pa0.v, vf[1][0], o1, 0, 0, 0);
            o1 = __builtin_amdgcn_mfma_f32_32x32x16_bf16(pa1.v, vf[1][1], o1, 0, 0, 0);
            __builtin_amdgcn_s_setprio(0);
        }
        __syncthreads();   // all waves done with buf[cur]; prefetch drained
    }

    // ---- merge kv-halves (pure sums): l via Lred, o via K/V LDS reuse ----
    float l2 = (la0 + la1);
    l2 += __shfl_xor(l2, 32);            // combine hi halves (same q)
    if (lane < 32) Lred[wave][lane] = l2;
    float* Ob = (qh == 0) ? (float*)&KsB[0][0] : (float*)&VtB[0][0];
    if (kh == 1) {
        #pragma unroll
        for (int r = 0; r < 16; ++r) {
            Ob[r * 64 + lane]        = o0[r];
            Ob[(16 + r) * 64 + lane] = o1[r];
        }
    }
    __syncthreads();
    if (kh == 0) {
        #pragma unroll
        for (int r = 0; r < 16; ++r) {
            int ql = (r & 3) + 8 * (r >> 2) + 4 * hi;       // q row 0..31
            float lt = Lred[2 * qh][ql] + Lred[2 * qh + 1][ql];
            int srow = qt * 64 + qh * 32 + ql;
            size_t idx = (((size_t)(b * SEQ + srow)) * NH + h) * HD + l31;
            float v0 = (o0[r] + Ob[r * 64 + lane]) / lt;
            float v1 = (o1[r] + Ob[(16 + r) * 64 + lane]) / lt;
            O[idx]      = f2bf(v0);
            O[idx + 32] = f2bf(v1);
        }
    }
}

extern "C" void kernel_launch(void* const* d_in, const int* in_sizes, int n_in,
                              void* d_out, int out_size, void* d_ws, size_t ws_size,
                              hipStream_t stream) {
    const float* x     = (const float*)d_in[0];
    const float* w_qkv = (const float*)d_in[1];
    const float* b_qkv = (const float*)d_in[2];
    const float* w_out = (const float*)d_in[3];
    const float* b_out = (const float*)d_in[4];

    u16* qkv    = (u16*)d_ws;                       // Q | K | V^T, each PART
    u16* attn   = qkv + (size_t)3 * PART;           // PART bf16 (B,S,H,HD)
    u16* xb     = attn + (size_t)PART;              // PART bf16 (x converted)
    u16* wt_qkv = xb + (size_t)PART;                // 1536*512 bf16
    u16* wt_out = wt_qkv + (size_t)(3 * DM) * DM;   // 512*512 bf16

    const int M = BATCH * SEQ;                      // 8192

    prep_k<<<dim3(512, 1, 3), 256, 0, stream>>>(x, xb, w_qkv, wt_qkv,
                                                w_out, wt_out);

    dim3 g1(M / 128, (3 * DM) / 128);               // 64 x 12
    gemm_k<0><<<g1, 256, 0, stream>>>(xb, wt_qkv, b_qkv, qkv, M, 3 * DM, DM);

    dim3 g2(BATCH * NH, 32);                        // bh x qt (big-first LPT)
    attn_k<<<g2, 256, 0, stream>>>(qkv, qkv + PART, qkv + 2 * (size_t)PART, attn);

    dim3 g3(M / 64, DM / 128);                      // 128 x 4 = 512 blocks
    gemm_k<1><<<g3, 256, 0, stream>>>(attn, wt_out, b_out, (float*)d_out, M, DM, DM);
}